// Round 1
// baseline (136.333 us; speedup 1.0000x reference)
//
#include <hip/hip_runtime.h>

// Haar wavelet decomposition of channel 0 of (32,3,512,512) fp32.
// Output (32,4,256,256): bands ll,lh,hl,hh.
// One thread = 2 output columns: 2x float4 loads, 4x float2 stores.
__global__ __launch_bounds__(256) void haar_kernel(const float* __restrict__ x,
                                                   float* __restrict__ out) {
    int tid = blockIdx.x * blockDim.x + threadIdx.x;  // total 32*256*128 = 1<<20
    int j2 = tid & 127;           // which pair of output cols (j = 2*j2, 2*j2+1)
    int i  = (tid >> 7) & 255;    // output row
    int b  = tid >> 15;           // batch

    const float* base = x + (size_t)b * 3 * 512 * 512;        // channel 0 slab
    const float4 r0 = *(const float4*)(base + (2 * i)     * 512 + 4 * j2);
    const float4 r1 = *(const float4*)(base + (2 * i + 1) * 512 + 4 * j2);

    float a0 = r0.x, b0 = r0.y, a1 = r0.z, b1 = r0.w;   // even row
    float c0 = r1.x, d0 = r1.y, c1 = r1.z, d1 = r1.w;   // odd row

    float2 ll = make_float2((a0 + b0 + c0 + d0) * 0.5f, (a1 + b1 + c1 + d1) * 0.5f);
    float2 lh = make_float2((a0 + b0 - c0 - d0) * 0.5f, (a1 + b1 - c1 - d1) * 0.5f);
    float2 hl = make_float2((a0 - b0 + c0 - d0) * 0.5f, (a1 - b1 + c1 - d1) * 0.5f);
    float2 hh = make_float2((a0 - b0 - c0 + d0) * 0.5f, (a1 - b1 - c1 + d1) * 0.5f);

    // out[b][band][i][2*j2], band stride = 256*256 floats = 32768 float2
    float2* o = (float2*)(out + (size_t)b * 4 * 65536 + i * 256 + 2 * j2);
    o[0]     = ll;
    o[32768] = lh;
    o[65536] = hl;
    o[98304] = hh;
}

extern "C" void kernel_launch(void* const* d_in, const int* in_sizes, int n_in,
                              void* d_out, int out_size, void* d_ws, size_t ws_size,
                              hipStream_t stream) {
    const float* x = (const float*)d_in[0];
    float* out = (float*)d_out;
    haar_kernel<<<4096, 256, 0, stream>>>(x, out);
}

// Round 2
// 134.882 us; speedup vs baseline: 1.0108x; 1.0108x over previous
//
#include <hip/hip_runtime.h>

// Haar wavelet decomposition of channel 0 of (32,3,512,512) fp32.
// Output (32,4,256,256): bands ll,lh,hl,hh.
// One thread = 4 output columns: 4x float4 loads (2 per input row),
// 4x float4 stores (one per band). A 64-lane wave covers one full
// input row-pair (2x 2KB contiguous) and one full output row per band
// (1KB contiguous per store instruction).
__global__ __launch_bounds__(256) void haar_kernel(const float* __restrict__ x,
                                                   float* __restrict__ out) {
    int tid = blockIdx.x * blockDim.x + threadIdx.x;  // total 32*256*64 = 1<<19
    int j4 = tid & 63;            // group of 4 output cols: j = 4*j4 .. 4*j4+3
    int i  = (tid >> 6) & 255;    // output row
    int b  = tid >> 14;           // batch

    const float* base = x + (size_t)b * 3 * 512 * 512;        // channel 0 slab
    const float* r0p = base + (2 * i)     * 512 + 8 * j4;
    const float* r1p = base + (2 * i + 1) * 512 + 8 * j4;
    const float4 r0a = *(const float4*)(r0p);
    const float4 r0b = *(const float4*)(r0p + 4);
    const float4 r1a = *(const float4*)(r1p);
    const float4 r1b = *(const float4*)(r1p + 4);

    // column pairs k=0..3: (a,b) from even row, (c,d) from odd row
    float a[4] = {r0a.x, r0a.z, r0b.x, r0b.z};
    float bb[4] = {r0a.y, r0a.w, r0b.y, r0b.w};
    float c[4] = {r1a.x, r1a.z, r1b.x, r1b.z};
    float d[4] = {r1a.y, r1a.w, r1b.y, r1b.w};

    float4 ll, lh, hl, hh;
    float* llp = &ll.x; float* lhp = &lh.x; float* hlp = &hl.x; float* hhp = &hh.x;
#pragma unroll
    for (int k = 0; k < 4; ++k) {
        float s_ab = a[k] + bb[k], d_ab = a[k] - bb[k];
        float s_cd = c[k] + d[k],  d_cd = c[k] - d[k];
        llp[k] = (s_ab + s_cd) * 0.5f;
        lhp[k] = (s_ab - s_cd) * 0.5f;
        hlp[k] = (d_ab + d_cd) * 0.5f;
        hhp[k] = (d_ab - d_cd) * 0.5f;
    }

    // out[b][band][i][4*j4], band stride = 256*256 floats = 16384 float4
    float4* o = (float4*)(out + (size_t)b * 4 * 65536 + i * 256 + 4 * j4);
    o[0]     = ll;
    o[16384] = lh;
    o[32768] = hl;
    o[49152] = hh;
}

extern "C" void kernel_launch(void* const* d_in, const int* in_sizes, int n_in,
                              void* d_out, int out_size, void* d_ws, size_t ws_size,
                              hipStream_t stream) {
    const float* x = (const float*)d_in[0];
    float* out = (float*)d_out;
    haar_kernel<<<2048, 256, 0, stream>>>(x, out);
}